// Round 7
// baseline (137.747 us; speedup 1.0000x reference)
//
#include <hip/hip_runtime.h>
#include <math.h>

#define NN_ 256      // nodes per graph
#define BB_ 64       // batch
#define FF_ 5        // features
#define NE_ 65536    // NN_*NN_

// workspace layout in floats (~1 MB, L2/L3-resident)
// Operator planes WITHOUT dis factors: S_l[r][c] = 0.45 * z_l(r,c) * W(r,c)
// (dis applied in the chain kernel via DX = dis*X and dis^2 on the sum).
// Chain stage: DY[c] = 0.1*DX[c] + dis_c^2 * sum_r S[r*256+c]*DX[r]  (coalesced)
#define OFF_SA  0        // 0.45*W           (layers 1 and 3)
#define OFF_S1  65536    // 0.45*z0*W        (layer 0)
#define OFF_S3  131072   // 0.45*z1*W        (layer 2, relu)
#define OFF_S5  196608   // 0.45*z2*W        (layer 4)
#define OFF_DIS 262144   // 256 floats: dis

// ---------------------------------------------------------------------------
// K1: block i, thread k. One p gather per thread -> (a) |w| tree-reduce to
// dis_i, (b) the same signed w becomes operator row i: 4 planes written
// coalesced with z_l from coalesced u_rb reads. No cross-block deps.
// Block 0 lane 0: scalar tail (kld_loss, drop_rates).
// ---------------------------------------------------------------------------
__global__ __launch_bounds__(256) void build_all(
    const float* __restrict__ p, const float* __restrict__ a_uc,
    const float* __restrict__ b_uc, const float* __restrict__ u_pi,
    const float* __restrict__ u_rb, float* __restrict__ ws,
    float* __restrict__ out) {
  const int i = blockIdx.x, k = threadIdx.x;
  const int t = (i >= k) ? (i * (i + 1) / 2 + k) : (k * (k + 1) / 2 + i);
  const float w = p[t];

  __shared__ float sh[NN_];
  sh[k] = fabsf(w);
  __syncthreads();
  for (int s = NN_ / 2; s > 0; s >>= 1) {
    if (k < s) sh[k] += sh[k + s];
    __syncthreads();
  }
  if (k == 0) {
    const float deg = sh[0];
    ws[OFF_DIS + i] = (deg > 0.0f) ? (1.0f / sqrtf(deg)) : 0.0f;
  }

  // per-thread logits (cheap, avoids any dependency)
  float lg[3];
#pragma unroll
  for (int l = 0; l < 3; ++l) {
    const float au = fmaxf(a_uc[l], -10.0f);
    const float bu = fminf(fmaxf(b_uc[l], -10.0f), 50.0f);
    const float a = log1pf(expf(au));
    const float b = log1pf(expf(bu));
    const float up = fminf(fmaxf(u_pi[l], 1e-6f), 1.0f - 1e-6f);
    const float pi = powf(1.0f - powf(up, 1.0f / b), 1.0f / a);
    lg[l] = logf(pi) - log1pf(-pi);
  }

  const int idx = i * NN_ + k;
  const float inv_temp = 1.0f / 0.6f;
  const float ws045 = 0.45f * w;
  ws[OFF_SA + idx] = ws045;

  float u, v, z;
  u = fminf(fmaxf(u_rb[0 * NE_ + idx], 1e-6f), 1.0f - 1e-6f);
  v = (lg[0] + logf(u) - log1pf(-u)) * inv_temp;
  z = 1.0f / (1.0f + expf(-v));
  ws[OFF_S1 + idx] = z * ws045;

  u = fminf(fmaxf(u_rb[1 * NE_ + idx], 1e-6f), 1.0f - 1e-6f);
  v = (lg[1] + logf(u) - log1pf(-u)) * inv_temp;
  z = 1.0f / (1.0f + expf(-v));
  ws[OFF_S3 + idx] = z * ws045;

  u = fminf(fmaxf(u_rb[2 * NE_ + idx], 1e-6f), 1.0f - 1e-6f);
  v = (lg[2] + logf(u) - log1pf(-u)) * inv_temp;
  z = 1.0f / (1.0f + expf(-v));
  ws[OFF_S5 + idx] = z * ws045;

  if (i == 0 && k == 0) {
    float kld_sum = 0.0f;
    const float euler = 0.577215664901532f;
    for (int l = 0; l < 3; ++l) {
      const float au = fmaxf(a_uc[l], -10.0f);
      const float bu = fminf(fmaxf(b_uc[l], -10.0f), 50.0f);
      const float a = log1pf(expf(au));
      const float b = log1pf(expf(bu));
      const float up = fminf(fmaxf(u_pi[l], 1e-6f), 1.0f - 1e-6f);
      const float pi = powf(1.0f - powf(up, 1.0f / b), 1.0f / a);
      out[193 + l] = pi;  // drop_rates
      float x = b, dg = 0.0f;
      while (x < 6.0f) { dg -= 1.0f / x; x += 1.0f; }
      const float inv = 1.0f / x, inv2 = inv * inv;
      dg += logf(x) - 0.5f * inv
            - inv2 * (1.0f / 12.0f - inv2 * (1.0f / 120.0f - inv2 * (1.0f / 252.0f)));
      kld_sum += (1.0f - 0.8f / a) * (-euler - dg - 1.0f / b)
                 + logf(a * b + 1e-10f) - logf(0.8f) - (b - 1.0f) / b;
    }
    out[192] = kld_sum;  // kld_loss
  }
}

// ---------------------------------------------------------------------------
// K2: per-batch chain + head. 64 blocks x 1024 threads. State in LDS is the
// dis-scaled DX (ping-pong, padded rows of 8). Inner loop identical to R6:
// coalesced operator load + uniform LDS float4 broadcast + 5 FMA.
// relu commutes with the dis scaling (dis >= 0); unscale at last stage.
// ---------------------------------------------------------------------------
__global__ __launch_bounds__(1024) void batch_chain(
    const float* __restrict__ x0g, const float* __restrict__ ws,
    const float* __restrict__ lin_w, const float* __restrict__ lin_b,
    const float* __restrict__ fc_w, const float* __restrict__ fc_b,
    float* __restrict__ out) {
  const int b = blockIdx.x, tid = threadIdx.x;
  __shared__ float xbuf[2][NN_ * 8];   // 16 KB
  __shared__ float part[4 * NN_ * 8];  // 32 KB (reused by head)
  __shared__ float sdis[NN_], sdis2[NN_], sinv[NN_];  // 3 KB
  float* Xc = xbuf[0];
  float* Xn = xbuf[1];

  if (tid < NN_) {
    const float d = ws[OFF_DIS + tid];
    sdis[tid] = d;
    sdis2[tid] = d * d;
    sinv[tid] = (d > 0.0f) ? (1.0f / d) : 0.0f;
  }
  __syncthreads();

  // stage DX0[i][f] = dis_i * x[b][i][f] into padded LDS rows [i][8]
  for (int idx = tid; idx < NN_ * FF_; idx += 1024) {
    const int i = idx / 5, f = idx - 5 * i;
    Xc[i * 8 + f] = sdis[i] * x0g[b * (NN_ * FF_) + idx];
  }
  __syncthreads();

  const int q = tid >> 8;      // k-quarter 0..3
  const int j = tid & 255;     // output node
  const int k0 = q * 64;

#pragma unroll
  for (int l = 0; l < 5; ++l) {
    const float* __restrict__ Op =
        ws + (l == 0 ? OFF_S1 : l == 2 ? OFF_S3 : l == 4 ? OFF_S5 : OFF_SA)
        + j;
    float4 a03 = {0.f, 0.f, 0.f, 0.f};
    float a4 = 0.f;
#pragma unroll 8
    for (int k = k0; k < k0 + 64; ++k) {
      const float w = Op[k * NN_];                      // coalesced global
      const float4 xv = *(const float4*)(Xc + k * 8);   // LDS broadcast
      const float x4 = Xc[k * 8 + 4];
      a03.x += w * xv.x; a03.y += w * xv.y;
      a03.z += w * xv.z; a03.w += w * xv.w;
      a4 += w * x4;
    }
    *(float4*)(part + tid * 8) = a03;   // part[q][j][0..3]
    part[tid * 8 + 4] = a4;
    __syncthreads();
    // combine quarters: DY = 0.1*DX + dis^2 * S ; relu at l==2; unscale l==4
    for (int idx = tid; idx < 2048; idx += 1024) {
      const int jj = idx >> 3;
      const float sum = part[idx] + part[2048 + idx] + part[4096 + idx] +
                        part[6144 + idx];
      float y = 0.1f * Xc[idx] + sdis2[jj] * sum;
      if (l == 2) y = fmaxf(y, 0.f);
      if (l == 4) y *= sinv[jj];      // O = DY / dis  (unscaled output)
      Xn[idx] = y;
    }
    __syncthreads();
    float* t = Xc; Xc = Xn; Xn = t;
  }

  // head: Xc holds O (256 x 5, padded 8). relu(O@lin_w+lin_b) -> pool -> fc.
  const int k = tid & 127, seg = tid >> 7;  // 8 segs x 32 rows
  const float lw0 = lin_w[0 * 128 + k];
  const float lw1 = lin_w[1 * 128 + k];
  const float lw2 = lin_w[2 * 128 + k];
  const float lw3 = lin_w[3 * 128 + k];
  const float lw4 = lin_w[4 * 128 + k];
  const float lb = lin_b[k];
  float acc = 0.f;
  const int j0 = seg * 32;
#pragma unroll 4
  for (int jj = j0; jj < j0 + 32; ++jj) {
    const float4 ov = *(const float4*)(Xc + jj * 8);  // LDS broadcast
    const float o4 = Xc[jj * 8 + 4];
    const float v = lb + lw0 * ov.x + lw1 * ov.y + lw2 * ov.z +
                    lw3 * ov.w + lw4 * o4;
    acc += fmaxf(v, 0.f);
  }
  part[seg * 128 + k] = acc;
  __syncthreads();
  if (tid < 128) {
    float s = 0.f;
#pragma unroll
    for (int s8 = 0; s8 < 8; ++s8) s += part[s8 * 128 + tid];
    part[tid] = s;  // pooled[k]
  }
  __syncthreads();
  if (tid < 3) {
    float s = fc_b[tid];
    for (int kk = 0; kk < 128; ++kk) s += part[kk] * fc_w[kk * 3 + tid];
    out[b * 3 + tid] = s;
  }
}

// ---------------------------------------------------------------------------
extern "C" void kernel_launch(void* const* d_in, const int* in_sizes, int n_in,
                              void* d_out, int out_size, void* d_ws,
                              size_t ws_size, hipStream_t stream) {
  const float* x      = (const float*)d_in[0];
  const float* p      = (const float*)d_in[1];
  const float* a_uc   = (const float*)d_in[2];
  const float* b_uc   = (const float*)d_in[3];
  const float* u_pi   = (const float*)d_in[4];
  const float* u_rb   = (const float*)d_in[5];
  const float* lin_w  = (const float*)d_in[6];
  const float* lin_b  = (const float*)d_in[7];
  const float* fc_w   = (const float*)d_in[8];
  const float* fc_b   = (const float*)d_in[9];
  // d_in[10] edge_index, d_in[11] batch: fully deterministic, never read.
  float* out = (float*)d_out;
  float* ws  = (float*)d_ws;

  build_all<<<256, 256, 0, stream>>>(p, a_uc, b_uc, u_pi, u_rb, ws, out);
  batch_chain<<<64, 1024, 0, stream>>>(x, ws, lin_w, lin_b, fc_w, fc_b, out);
}